// Round 4
// baseline (39328.625 us; speedup 1.0000x reference)
//
#include <hip/hip_runtime.h>

#define BB 32
#define TT 2048
#define HH 256
#define NT 512

typedef unsigned long long ull;
typedef unsigned int uint;

__device__ __forceinline__ float sigm(float v) { return 1.0f / (1.0f + __expf(-v)); }

__device__ __forceinline__ ull aload64(const ull* p) {
  return __hip_atomic_load(p, __ATOMIC_RELAXED, __HIP_MEMORY_SCOPE_AGENT);
}
__device__ __forceinline__ void astore64(ull* p, ull v) {
  __hip_atomic_store(p, v, __ATOMIC_RELAXED, __HIP_MEMORY_SCOPE_AGENT);
}
__device__ __forceinline__ int aload(const int* p) {
  return __hip_atomic_load(p, __ATOMIC_RELAXED, __HIP_MEMORY_SCOPE_AGENT);
}
__device__ __forceinline__ void astore(int* p, int v) {
  __hip_atomic_store(p, v, __ATOMIC_RELAXED, __HIP_MEMORY_SCOPE_AGENT);
}

// ws layout: rmark[128] ints at +0 (r0=0..63, r1=64..127); rings at +4096:
//   ring0[2][8192] then ring1[2][8192], each pair = {tag(lo32), h_bits(hi32)}
__global__ __launch_bounds__(NT) void lstm_scan(
    const float* __restrict__ x,     // [B,T,H]
    const float* __restrict__ W,     // [L,4,H,2H]
    const float* __restrict__ bias,  // [L,4,H]
    float* __restrict__ out,         // [B,T,H] + hT[B,H] + cT[B,H]
    ull* __restrict__ ring,
    int* __restrict__ rmark)
{
    const int wg    = blockIdx.x;
    const int layer = wg >> 6;        // 0 or 1
    const int slice = wg & 63;
    const int hbase = slice << 2;
    const int tid   = threadIdx.x;
    const int b     = tid >> 4;       // 0..31
    const int u     = (tid >> 2) & 3;
    const int g     = tid & 3;        // 0=i 1=f 2=o 3=chat
    const int col   = hbase + u;

    int* r0 = rmark;
    int* r1 = rmark + 64;
    ull* ring0 = ring;
    ull* ring1 = ring + 2 * 8192;
    ull* ringL = layer ? ring1 : ring0;

    __shared__ float wlds[16][516];
    __shared__ float inp[BB][260];
    __shared__ float hrec[BB][260];

    for (int r = 0; r < 16; ++r) {
        const float* wrow = W + (((size_t)layer * 4 + (r >> 2)) * HH + (hbase + (r & 3))) * (2 * HH);
        for (int k = tid; k < 2 * HH; k += NT) wlds[r][k] = wrow[k];
    }
    __syncthreads();

    const int jj = g * 4 + u;
    const float bg = bias[((size_t)layer * 4 + g) * HH + col];
    const float4* wx4 = (const float4*)&wlds[jj][0];
    const float4* wh4 = (const float4*)&wlds[jj][256];

    // staging map: thread covers pairs [tid*16 .. tid*16+16) = batch pb, cols [pc, pc+16)
    const int pb = tid >> 4;
    const int pc = (tid & 15) << 4;

    float c_state = 0.f;

    for (int t = 0; t < TT; ++t) {
        // ---- phase A: poll tagged data, copy into LDS (one-way latency only) ----
        ull* rrec = ringL + ((t + 1) & 1) * 8192 + pb * HH + pc;  // h_l(t-1), tag t
        ull* rin  = ring0 + (t & 1) * 8192 + pb * HH + pc;        // h0(t), tag t+1 (layer 1)
        const uint wantr = (uint)t;
        const uint wanti = (uint)(t + 1);

        if (layer == 0) {
            const float4* src = (const float4*)(x + ((size_t)pb * TT + t) * HH + pc);
            float4 a0 = src[0], a1 = src[1], a2 = src[2], a3 = src[3];
            float4* dst = (float4*)&inp[pb][pc];
            dst[0] = a0; dst[1] = a1; dst[2] = a2; dst[3] = a3;
        }
        for (;;) {
            bool ok = true;
            ull v[16];
            #pragma unroll
            for (int j = 0; j < 16; ++j) v[j] = aload64(&rrec[j]);
            #pragma unroll
            for (int j = 0; j < 16; ++j) ok &= ((uint)v[j] == wantr);
            #pragma unroll
            for (int j = 0; j < 16; ++j) hrec[pb][pc + j] = __uint_as_float((uint)(v[j] >> 32));
            if (layer == 1) {
                ull w[16];
                #pragma unroll
                for (int j = 0; j < 16; ++j) w[j] = aload64(&rin[j]);
                #pragma unroll
                for (int j = 0; j < 16; ++j) ok &= ((uint)w[j] == wanti);
                #pragma unroll
                for (int j = 0; j < 16; ++j) inp[pb][pc + j] = __uint_as_float((uint)(w[j] >> 32));
            }
            if (__all(ok)) break;
            __builtin_amdgcn_s_sleep(1);
        }
        __syncthreads();
        if (tid == 0) astore(layer ? &r1[slice] : &r0[slice], t + 1);  // reads of step t done

        // ---- phase B: gates from LDS (h(-1)=0 handled by zero-init ring) ----
        const float4* xr = (const float4*)&inp[b][0];
        const float4* hr = (const float4*)&hrec[b][0];
        float acc = bg, acc2 = 0.f;
        #pragma unroll 8
        for (int c4 = 0; c4 < 32; ++c4) {
            float4 a = xr[2 * c4], a2v = xr[2 * c4 + 1];
            float4 w = wx4[2 * c4], w2 = wx4[2 * c4 + 1];
            acc  += a.x * w.x + a.y * w.y + a.z * w.z + a.w * w.w;
            acc2 += a2v.x * w2.x + a2v.y * w2.y + a2v.z * w2.z + a2v.w * w2.w;
        }
        #pragma unroll 8
        for (int c4 = 0; c4 < 32; ++c4) {
            float4 a = hr[2 * c4], a2v = hr[2 * c4 + 1];
            float4 w = wh4[2 * c4], w2 = wh4[2 * c4 + 1];
            acc  += a.x * w.x + a.y * w.y + a.z * w.z + a.w * w.w;
            acc2 += a2v.x * w2.x + a2v.y * w2.y + a2v.z * w2.z + a2v.w * w2.w;
        }
        acc += acc2;
        float f_ = __shfl_xor(acc, 1);
        float o_ = __shfl_xor(acc, 2);
        float q_ = __shfl_xor(acc, 3);
        float hn = 0.f;
        if (g == 0) {
            float ig = sigm(acc), fg = sigm(f_), og = sigm(o_), ch = tanhf(q_);
            c_state = fg * c_state + ig * ch;
            hn = og * tanhf(c_state);
        }

        // ---- phase C: write-gate (ring slot t&1 reusable?) — overlaps stragglers ----
        // layer0 writes ring0[t&1] (kills h0(t-2)): readers L0@t-1 (r0>=t), L1@t-2 (r1>=t-1)
        // layer1 writes ring1[t&1] (kills h1(t-2)): readers L1@t-1 (r1>=t)
        if (layer == 0) {
            if (tid < 64) { while (aload(&r0[tid]) < t) __builtin_amdgcn_s_sleep(1); }
            else if (tid < 128) { while (aload(&r1[tid - 64]) < t - 1) __builtin_amdgcn_s_sleep(1); }
        } else {
            if (tid < 64) { while (aload(&r1[tid]) < t) __builtin_amdgcn_s_sleep(1); }
        }
        __syncthreads();

        if (g == 0) {
            ull pv = ((ull)__float_as_uint(hn) << 32) | (uint)(t + 1);
            astore64(&ringL[(t & 1) * 8192 + b * HH + col], pv);
            if (layer == 1) {
                out[((size_t)b * TT + t) * HH + col] = hn;
                if (t == TT - 1) {
                    float* tail = out + (size_t)BB * TT * HH;
                    tail[b * HH + col] = hn;
                    tail[BB * HH + b * HH + col] = c_state;
                }
            }
        }
    }
}

extern "C" void kernel_launch(void* const* d_in, const int* in_sizes, int n_in,
                              void* d_out, int out_size, void* d_ws, size_t ws_size,
                              hipStream_t stream) {
    (void)in_sizes; (void)n_in; (void)out_size; (void)ws_size;
    const float* x    = (const float*)d_in[0];
    const float* W    = (const float*)d_in[1];
    const float* bias = (const float*)d_in[2];
    float* out  = (float*)d_out;
    int*   rmark = (int*)d_ws;
    ull*   ring  = (ull*)((char*)d_ws + 4096);  // 4*8192*8 = 256 KB

    hipMemsetAsync(d_ws, 0, 4096 + 4 * 8192 * sizeof(ull), stream);
    hipLaunchKernelGGL(lstm_scan, dim3(128), dim3(NT), 0, stream, x, W, bias, out, ring, rmark);
}

// Round 7
// 20914.473 us; speedup vs baseline: 1.8805x; 1.8805x over previous
//
#include <hip/hip_runtime.h>

#define BB 32
#define TT 2048
#define HH 256
#define NT 512

typedef unsigned long long ull;
typedef unsigned int uint;

__device__ __forceinline__ float sigm(float v) { return 1.0f / (1.0f + __expf(-v)); }

__device__ __forceinline__ int aload(const int* p) {
  return __hip_atomic_load(p, __ATOMIC_RELAXED, __HIP_MEMORY_SCOPE_AGENT);
}
__device__ __forceinline__ void astore(int* p, int v) {
  __hip_atomic_store(p, v, __ATOMIC_RELAXED, __HIP_MEMORY_SCOPE_AGENT);
}
__device__ __forceinline__ ull aload64(const ull* p) {
  return __hip_atomic_load(p, __ATOMIC_RELAXED, __HIP_MEMORY_SCOPE_AGENT);
}
__device__ __forceinline__ void astore64(ull* p, ull v) {
  __hip_atomic_store(p, v, __ATOMIC_RELAXED, __HIP_MEMORY_SCOPE_AGENT);
}

// ws: markers m0[64], m1[64] ints at +0; rings at +4096:
//   slot(layer,s) = 8192 pairs {tag(lo32), hbits(hi32)}, pair index = b*HH+col
__global__ __launch_bounds__(NT) void lstm_scan(
    const float* __restrict__ x,     // [B,T,H]
    const float* __restrict__ W,     // [L,4,H,2H]
    const float* __restrict__ bias,  // [L,4,H]
    float* __restrict__ out,         // [B,T,H] + hT[B,H] + cT[B,H]
    ull* __restrict__ ring,
    int* __restrict__ sync)
{
    const int wg    = blockIdx.x;
    const int layer = wg >> 6;        // 0 or 1
    const int slice = wg & 63;
    const int hbase = slice << 2;
    const int tid   = threadIdx.x;
    const int b     = tid >> 4;       // 0..31
    const int u     = (tid >> 2) & 3;
    const int g     = tid & 3;        // 0=i 1=f 2=o 3=chat
    const int col   = hbase + u;

    int* m0 = sync;
    int* m1 = sync + 64;
    ull* ring0 = ring;
    ull* ring1 = ring + 2 * 8192;
    ull* ringL = layer ? ring1 : ring0;

    __shared__ float wlds[16][516];
    __shared__ float inp[BB][260];
    __shared__ float hrec[BB][260];

    for (int r = 0; r < 16; ++r) {
        const float* wrow = W + (((size_t)layer * 4 + (r >> 2)) * HH + (hbase + (r & 3))) * (2 * HH);
        for (int k = tid; k < 2 * HH; k += NT) wlds[r][k] = wrow[k];
    }
    __syncthreads();

    const int jj = g * 4 + u;
    const float bg = bias[((size_t)layer * 4 + g) * HH + col];
    const float4* wx4 = (const float4*)&wlds[jj][0];
    const float4* wh4 = (const float4*)&wlds[jj][256];

    const int sb = tid & 31;          // x-staging map
    const int sk = (tid >> 5) << 4;

    float c_state = 0.f;

    for (int t = 0; t < TT; ++t) {
        // ===== phase A: stage inputs (batch-issue pending, done-mask, write-once LDS) =====
        const ull* rrec = ringL + ((t + 1) & 1) * 8192;  // h_l(t-1), tag t
        const ull* rin  = ring0 + (t & 1) * 8192;        // h0(t), tag t+1 (layer 1 only)
        const uint wantR = (uint)t;
        const uint wantI = (uint)(t + 1);

        if (layer == 0) {
            const float4* src = (const float4*)(x + ((size_t)sb * TT + t) * HH + sk);
            float4 a0 = src[0], a1 = src[1], a2 = src[2], a3 = src[3];
            float4* dst = (float4*)&inp[sb][sk];
            dst[0] = a0; dst[1] = a1; dst[2] = a2; dst[3] = a3;

            uint pend = 0xFFFFu;      // 16 recurrent pairs
            ull v[16];
            for (;;) {
                #pragma unroll
                for (int k = 0; k < 16; ++k)
                    if (pend & (1u << k)) v[k] = aload64(&rrec[k * 512 + tid]);
                #pragma unroll
                for (int k = 0; k < 16; ++k)
                    if (pend & (1u << k)) {
                        if ((uint)v[k] == wantR) {
                            int p = k * 512 + tid;
                            hrec[p >> 8][p & 255] = __uint_as_float((uint)(v[k] >> 32));
                            pend &= ~(1u << k);
                        }
                    }
                if (!pend) break;
                __builtin_amdgcn_s_sleep(1);
            }
            // WAR gate for publishing h0(t) over h0(t-2)
            if (tid < 64)       { while (aload(&m0[tid])      < t)     __builtin_amdgcn_s_sleep(1); }
            else if (tid < 128) { while (aload(&m1[tid - 64]) < t - 1) __builtin_amdgcn_s_sleep(1); }
        } else {
            uint pend = 0xFFFFFFFFu;  // 16 recurrent + 16 input pairs
            ull v[32];
            for (;;) {
                #pragma unroll
                for (int k = 0; k < 16; ++k)
                    if (pend & (1u << k)) v[k] = aload64(&rrec[k * 512 + tid]);
                #pragma unroll
                for (int k = 0; k < 16; ++k)
                    if (pend & (1u << (k + 16))) v[k + 16] = aload64(&rin[k * 512 + tid]);
                #pragma unroll
                for (int k = 0; k < 16; ++k)
                    if (pend & (1u << k)) {
                        if ((uint)v[k] == wantR) {
                            int p = k * 512 + tid;
                            hrec[p >> 8][p & 255] = __uint_as_float((uint)(v[k] >> 32));
                            pend &= ~(1u << k);
                        }
                    }
                #pragma unroll
                for (int k = 0; k < 16; ++k)
                    if (pend & (1u << (k + 16))) {
                        if ((uint)v[k + 16] == wantI) {
                            int p = k * 512 + tid;
                            inp[p >> 8][p & 255] = __uint_as_float((uint)(v[k + 16] >> 32));
                            pend &= ~(1u << (k + 16));
                        }
                    }
                if (!pend) break;
                __builtin_amdgcn_s_sleep(1);
            }
            // WAR gate for publishing h1(t) over h1(t-2)
            if (tid < 64) { while (aload(&m1[tid]) < t) __builtin_amdgcn_s_sleep(1); }
        }
        __syncthreads();
        if (tid == 0) astore(layer ? &m1[slice] : &m0[slice], t + 1);  // staged step t

        // ===== phase B: gates =====
        const float4* xr = (const float4*)&inp[b][0];
        const float4* hr = (const float4*)&hrec[b][0];
        float acc = bg, acc2 = 0.f;
        #pragma unroll 8
        for (int c4 = 0; c4 < 32; ++c4) {
            float4 a = xr[2 * c4], a2v = xr[2 * c4 + 1];
            float4 w = wx4[2 * c4], w2 = wx4[2 * c4 + 1];
            acc  += a.x * w.x + a.y * w.y + a.z * w.z + a.w * w.w;
            acc2 += a2v.x * w2.x + a2v.y * w2.y + a2v.z * w2.z + a2v.w * w2.w;
        }
        #pragma unroll 8
        for (int c4 = 0; c4 < 32; ++c4) {
            float4 a = hr[2 * c4], a2v = hr[2 * c4 + 1];
            float4 w = wh4[2 * c4], w2 = wh4[2 * c4 + 1];
            acc  += a.x * w.x + a.y * w.y + a.z * w.z + a.w * w.w;
            acc2 += a2v.x * w2.x + a2v.y * w2.y + a2v.z * w2.z + a2v.w * w2.w;
        }
        acc += acc2;
        float f_ = __shfl_xor(acc, 1);
        float o_ = __shfl_xor(acc, 2);
        float q_ = __shfl_xor(acc, 3);
        if (g == 0) {
            float ig = sigm(acc), fg = sigm(f_), og = sigm(o_), ch = tanhf(q_);
            c_state = fg * c_state + ig * ch;
            float hn = og * tanhf(c_state);
            // publish tagged pair, fire-and-forget (visibility = the flag itself)
            ull pv = ((ull)__float_as_uint(hn) << 32) | (ull)(uint)(t + 1);
            astore64(&ringL[(t & 1) * 8192 + b * HH + col], pv);
            if (layer == 1) {
                out[((size_t)b * TT + t) * HH + col] = hn;
                if (t == TT - 1) {
                    float* tail = out + (size_t)BB * TT * HH;
                    tail[b * HH + col] = hn;
                    tail[BB * HH + b * HH + col] = c_state;
                }
            }
        }
        __syncthreads();
    }
}

extern "C" void kernel_launch(void* const* d_in, const int* in_sizes, int n_in,
                              void* d_out, int out_size, void* d_ws, size_t ws_size,
                              hipStream_t stream) {
    (void)in_sizes; (void)n_in; (void)out_size; (void)ws_size;
    const float* x    = (const float*)d_in[0];
    const float* W    = (const float*)d_in[1];
    const float* bias = (const float*)d_in[2];
    float* out  = (float*)d_out;
    int*   sync = (int*)d_ws;
    ull*   ring = (ull*)((char*)d_ws + 4096);  // 4 slots x 64KB = 256 KB

    hipMemsetAsync(d_ws, 0, 4096 + 4 * 8192 * sizeof(ull), stream);  // markers + ring tags
    hipLaunchKernelGGL(lstm_scan, dim3(128), dim3(NT), 0, stream, x, W, bias, out, ring, sync);
}

// Round 8
// 13123.065 us; speedup vs baseline: 2.9969x; 1.5937x over previous
//
#include <hip/hip_runtime.h>

#define BB 32
#define TT 2048
#define HH 256
#define QB 8    // batches per community
#define NT 512

typedef unsigned long long ull;
typedef unsigned int uint;

__device__ __forceinline__ float sigm(float v) { return 1.0f / (1.0f + __expf(-v)); }

__device__ __forceinline__ int aload(const int* p) {
  return __hip_atomic_load(p, __ATOMIC_RELAXED, __HIP_MEMORY_SCOPE_AGENT);
}
__device__ __forceinline__ void astore(int* p, int v) {
  __hip_atomic_store(p, v, __ATOMIC_RELAXED, __HIP_MEMORY_SCOPE_AGENT);
}
__device__ __forceinline__ ull aload64(const ull* p) {
  return __hip_atomic_load(p, __ATOMIC_RELAXED, __HIP_MEMORY_SCOPE_AGENT);
}
__device__ __forceinline__ void astore64(ull* p, ull v) {
  __hip_atomic_store(p, v, __ATOMIC_RELAXED, __HIP_MEMORY_SCOPE_AGENT);
}

// Communities: c = layer*4 + grp (8 total), 16 WGs each (unit-groups), XCD-aligned (c = bid&7).
// ws: markers m[8][16] ints at +0; rings at +4096: per community 2 slots x 2048 pairs
//     {tag(lo32), hbits(hi32)}, pair idx = bl*256 + col. 32 KB/community, 256 KB total.
__global__ __launch_bounds__(NT) void lstm_scan(
    const float* __restrict__ x,     // [B,T,H]
    const float* __restrict__ W,     // [L,4,H,2H]
    const float* __restrict__ bias,  // [L,4,H]
    float* __restrict__ out,         // [B,T,H] + hT[B,H] + cT[B,H]
    ull* __restrict__ ring,
    int* __restrict__ sync)
{
    const int bid   = blockIdx.x;
    const int c     = bid & 7;        // community == XCD slot
    const int ug    = bid >> 3;       // unit group 0..15
    const int layer = c >> 2;
    const int grp   = c & 3;          // batch group
    const int tid   = threadIdx.x;
    const int bl    = tid & 7;        // local batch
    const int gate  = (tid >> 3) & 3; // 0=i 1=f 2=o 3=chat
    const int unit  = tid >> 5;       // 0..15
    const int col   = ug * 16 + unit;
    const int bglob = grp * 8 + bl;

    int* mOwn = sync + c * 16;
    int* mSib = sync + (4 + grp) * 16;             // layer-1 community, same grp
    ull* ringOwn = ring + (size_t)c * 4096;
    ull* ringIn  = ring + (size_t)grp * 4096;      // layer-0 community, same grp

    __shared__ float wlds[64][516];  // row r = unit*4+gate; banks 4r+k cover all 32
    __shared__ float inp[QB][260];
    __shared__ float hrec[QB][260];

    for (int rr = 0; rr < 64; ++rr) {
        const float* wrow =
            W + (((size_t)layer * 4 + (rr & 3)) * HH + (ug * 16 + (rr >> 2))) * (2 * HH);
        wlds[rr][tid] = wrow[tid];
    }
    __syncthreads();

    const int r = unit * 4 + gate;
    const float bg = bias[((size_t)layer * 4 + gate) * HH + col];
    const float4* wx4 = (const float4*)&wlds[r][0];
    const float4* wh4 = (const float4*)&wlds[r][256];

    const int prow = tid >> 6;          // staging row (local batch)
    const int pcol = (tid & 63) << 2;   // staging col base (4 elems/thread)

    float c_state = 0.f;

    for (int t = 0; t < TT; ++t) {
        // ---- (1) input stage: x (layer0) or h0 ring poll (layer1) ----
        if (layer == 0) {
            *(float4*)&inp[prow][pcol] =
                *(const float4*)(x + ((size_t)(grp * 8 + prow) * TT + t) * HH + pcol);
        } else {
            const ull* rin = ringIn + (t & 1) * 2048 + 4 * tid;
            const uint want = (uint)(t + 1);
            uint pend = 0xFu; ull v[4];
            for (;;) {
                #pragma unroll
                for (int j = 0; j < 4; ++j)
                    if (pend & (1u << j)) v[j] = aload64(&rin[j]);
                #pragma unroll
                for (int j = 0; j < 4; ++j)
                    if (pend & (1u << j))
                        if ((uint)v[j] == want) {
                            inp[prow][pcol + j] = __uint_as_float((uint)(v[j] >> 32));
                            pend &= ~(1u << j);
                        }
                if (!pend) break;
                __builtin_amdgcn_s_sleep(1);
            }
        }
        __syncthreads();  // inp ready

        // ---- (2) x-part dot (K=256) — recurrent h arrives under this compute ----
        const float4* xr = (const float4*)&inp[bl][0];
        float acc = bg, acc2 = 0.f;
        #pragma unroll 8
        for (int c4 = 0; c4 < 32; ++c4) {
            float4 a = xr[2 * c4], a2 = xr[2 * c4 + 1];
            float4 w = wx4[2 * c4], w2 = wx4[2 * c4 + 1];
            acc  += a.x * w.x + a.y * w.y + a.z * w.z + a.w * w.w;
            acc2 += a2.x * w2.x + a2.y * w2.y + a2.z * w2.z + a2.w * w2.w;
        }

        // ---- (3) recurrent poll -> hrec (4 pairs/thread) ----
        {
            const ull* rr_ = ringOwn + ((t + 1) & 1) * 2048 + 4 * tid;
            const uint want = (uint)t;
            uint pend = 0xFu; ull v[4];
            for (;;) {
                #pragma unroll
                for (int j = 0; j < 4; ++j)
                    if (pend & (1u << j)) v[j] = aload64(&rr_[j]);
                #pragma unroll
                for (int j = 0; j < 4; ++j)
                    if (pend & (1u << j))
                        if ((uint)v[j] == want) {
                            hrec[prow][pcol + j] = __uint_as_float((uint)(v[j] >> 32));
                            pend &= ~(1u << j);
                        }
                if (!pend) break;
                __builtin_amdgcn_s_sleep(1);
            }
        }
        // ---- (4) WAR gates (community-local; overlaps stragglers) ----
        if (tid < 16)                    { while (aload(&mOwn[tid]) < t)          __builtin_amdgcn_s_sleep(1); }
        else if (layer == 0 && tid < 32) { while (aload(&mSib[tid - 16]) < t - 1) __builtin_amdgcn_s_sleep(1); }
        __syncthreads();  // hrec ready + gates passed
        if (tid == 0) astore(&mOwn[ug], t + 1);  // staged step t (inp + hrec consumed)

        // ---- (5) h-part dot (K=256) + activations + publish ----
        const float4* hr = (const float4*)&hrec[bl][0];
        #pragma unroll 8
        for (int c4 = 0; c4 < 32; ++c4) {
            float4 a = hr[2 * c4], a2 = hr[2 * c4 + 1];
            float4 w = wh4[2 * c4], w2 = wh4[2 * c4 + 1];
            acc  += a.x * w.x + a.y * w.y + a.z * w.z + a.w * w.w;
            acc2 += a2.x * w2.x + a2.y * w2.y + a2.z * w2.z + a2.w * w2.w;
        }
        acc += acc2;
        float f_ = __shfl_xor(acc, 8);
        float o_ = __shfl_xor(acc, 16);
        float q_ = __shfl_xor(acc, 24);
        if (gate == 0) {
            float ig = sigm(acc), fg = sigm(f_), og = sigm(o_), ch = tanhf(q_);
            c_state = fg * c_state + ig * ch;
            float hn = og * tanhf(c_state);
            astore64(&ringOwn[(t & 1) * 2048 + bl * 256 + col],
                     ((ull)__float_as_uint(hn) << 32) | (ull)(uint)(t + 1));
            if (layer == 1) {
                out[((size_t)bglob * TT + t) * HH + col] = hn;
                if (t == TT - 1) {
                    float* tail = out + (size_t)BB * TT * HH;
                    tail[bglob * HH + col] = hn;               // hT (last layer)
                    tail[BB * HH + bglob * HH + col] = c_state; // cT (last layer)
                }
            }
        }
        __syncthreads();  // protect inp/hrec before next iteration overwrites
    }
}

extern "C" void kernel_launch(void* const* d_in, const int* in_sizes, int n_in,
                              void* d_out, int out_size, void* d_ws, size_t ws_size,
                              hipStream_t stream) {
    (void)in_sizes; (void)n_in; (void)out_size; (void)ws_size;
    const float* x    = (const float*)d_in[0];
    const float* W    = (const float*)d_in[1];
    const float* bias = (const float*)d_in[2];
    float* out  = (float*)d_out;
    int*   sync = (int*)d_ws;
    ull*   ring = (ull*)((char*)d_ws + 4096);  // 8 communities x 32 KB = 256 KB

    hipMemsetAsync(d_ws, 0, 4096 + 8 * 4096 * sizeof(ull), stream);  // markers + ring tags
    hipLaunchKernelGGL(lstm_scan, dim3(128), dim3(NT), 0, stream, x, W, bias, out, ring, sync);
}